// Round 1
// baseline (190.856 us; speedup 1.0000x reference)
//
#include <hip/hip_runtime.h>

// NonLocalBlock (SAGAN non-local) fused pipeline for MI355X / gfx950.
// B=8, Cin=256, H=W=64 (HW=4096), Cout=512. All GEMMs via fp16 MFMA
// (16x16x32, fp32 accum). Workspace layout (needs ~46 MB of d_ws):
//   [0,16MB)   xT   fp16 [8][4096][256]   (x transposed, n-major)
//   [16,20MB)  Q    fp16 [8][4096][64]
//   [20,21MB)  Kp   fp16 [8][1024][64]
//   [21,25MB)  V    fp16 [8][256][1024]
//   [25MB+0)   Wproj fp16 [384][256]  (theta|phi|g, pre-scaled)
//   [25MB+512K) Wcat fp16 [512][512]  (gamma*s/sqrt2*w_o | s/sqrt2*w_res)
//   [26,46MB)  F    fp16 [8][320][4096] full-res phi|g proj; att aliases here
//                         (att fp16 [8][4096][256], written after pool consumed F)

typedef _Float16 f16;
typedef f16 f16x8 __attribute__((ext_vector_type(8)));
typedef float f32x4 __attribute__((ext_vector_type(4)));

#define MFMA16(a, b, c) __builtin_amdgcn_mfma_f32_16x16x32_f16((a), (b), (c), 0, 0, 0)

__device__ __forceinline__ void gload16(const void* src, void* dst_lds) {
  __builtin_amdgcn_global_load_lds(
      (const __attribute__((address_space(1))) void*)src,
      (__attribute__((address_space(3))) void*)dst_lds, 16, 0, 0);
}

// -------------------------------------------------------------------------
// Weight prep: fp32 -> fp16 with EqualizedConv scale folded in.
// Wproj rows: [0,64)=w_theta, [64,128)=w_phi, [128,384)=w_g, each *sqrt(2/256).
// Wcat [512][512]: cols<256 = w_o*gamma*s/sqrt2 ; cols>=256 = w_res*s/sqrt2.
__global__ void k_prep_w(const float* __restrict__ wt, const float* __restrict__ wp,
                         const float* __restrict__ wg, const float* __restrict__ wo,
                         const float* __restrict__ wr, const float* __restrict__ gamma,
                         f16* __restrict__ Wproj, f16* __restrict__ Wcat) {
  int i = blockIdx.x * 256 + threadIdx.x;
  const float s = 0.08838834764831845f;    // sqrt(2/256)
  const float is2 = 0.7071067811865476f;   // 1/sqrt(2)
  if (i < 384 * 256) {
    float v = (i < 64 * 256) ? wt[i]
              : (i < 128 * 256 ? wp[i - 64 * 256] : wg[i - 128 * 256]);
    Wproj[i] = (f16)(v * s);
  } else {
    int j = i - 384 * 256;
    if (j < 512 * 512) {
      int r = j >> 9, c = j & 511;
      float v = (c < 256) ? wo[r * 256 + c] * (gamma[0] * s * is2)
                          : wr[r * 256 + (c - 256)] * (s * is2);
      Wcat[j] = (f16)v;
    }
  }
}

// -------------------------------------------------------------------------
// Transpose x [b][256][4096] fp32 -> xT [b][4096][256] fp16 via 64x64 LDS tiles.
__global__ void k_transpose(const float* __restrict__ x, f16* __restrict__ xT) {
  __shared__ f16 tile[64 * 72];  // [c][n], pad 72 to break some conflicts
  int b = blockIdx.z, nt = blockIdx.y, ct = blockIdx.x;
  int t = threadIdx.x;
  {
    int c = t >> 2, nch = (t & 3) * 16;
    const float* src = x + (((size_t)b * 256 + ct * 64 + c) << 12) + nt * 64 + nch;
    float4 v0 = *(const float4*)(src);
    float4 v1 = *(const float4*)(src + 4);
    float4 v2 = *(const float4*)(src + 8);
    float4 v3 = *(const float4*)(src + 12);
    f16x8 a = {(f16)v0.x, (f16)v0.y, (f16)v0.z, (f16)v0.w,
               (f16)v1.x, (f16)v1.y, (f16)v1.z, (f16)v1.w};
    f16x8 bb = {(f16)v2.x, (f16)v2.y, (f16)v2.z, (f16)v2.w,
                (f16)v3.x, (f16)v3.y, (f16)v3.z, (f16)v3.w};
    *(f16x8*)&tile[c * 72 + nch] = a;
    *(f16x8*)&tile[c * 72 + nch + 8] = bb;
  }
  __syncthreads();
  {
    int n = t >> 2, cch = (t & 3) * 16;
    f16 tmp[16];
#pragma unroll
    for (int i = 0; i < 16; i++) tmp[i] = tile[(cch + i) * 72 + n];
    f16x8 a, bb;
#pragma unroll
    for (int i = 0; i < 8; i++) { a[i] = tmp[i]; bb[i] = tmp[8 + i]; }
    f16* dst = xT + (((size_t)b * 4096 + nt * 64 + n) << 8) + ct * 64 + cch;
    *(f16x8*)dst = a;
    *(f16x8*)(dst + 8) = bb;
  }
}

// -------------------------------------------------------------------------
// Q GEMM: Q[b][n][ch] = sum_k xT[b][n][k] * Wproj[ch][k], ch in [0,64).
// Tile: 128n x 64ch, BK=64, 4 waves each [32n x 64ch].
__global__ void k_gemm_q(const f16* __restrict__ xT, const f16* __restrict__ Wproj,
                         f16* __restrict__ Q) {
  __shared__ f16 Alds[128 * 64];
  __shared__ f16 Blds[64 * 64];
  int b = blockIdx.y, nt = blockIdx.x;
  int lane = threadIdx.x & 63, wave = threadIdx.x >> 6;
  f32x4 acc[2][4];
#pragma unroll
  for (int mf = 0; mf < 2; mf++)
#pragma unroll
    for (int nf = 0; nf < 4; nf++) acc[mf][nf] = (f32x4){0, 0, 0, 0};
  const f16* Abase = xT + (((size_t)b * 4096 + nt * 128) << 8);
  for (int k0 = 0; k0 < 256; k0 += 64) {
    __syncthreads();
#pragma unroll
    for (int i = 0; i < 4; i++) {
      int chunk = i * 256 + threadIdx.x;
      int row = chunk >> 3, cc = chunk & 7, scc = cc ^ (row & 7);
      gload16(Abase + (row << 8) + k0 + scc * 8, (char*)Alds + (i * 256 + wave * 64) * 16);
    }
#pragma unroll
    for (int i = 0; i < 2; i++) {
      int chunk = i * 256 + threadIdx.x;
      int row = chunk >> 3, cc = chunk & 7, scc = cc ^ (row & 7);
      gload16(Wproj + (row << 8) + k0 + scc * 8, (char*)Blds + (i * 256 + wave * 64) * 16);
    }
    __syncthreads();
#pragma unroll
    for (int ks = 0; ks < 2; ks++) {
      int cb = ((lane >> 4) * 8 + ks * 32) * 2;
      f16x8 af[2], bf[4];
#pragma unroll
      for (int mf = 0; mf < 2; mf++) {
        int row = wave * 32 + mf * 16 + (lane & 15);
        af[mf] = *(const f16x8*)((const char*)Alds + row * 128 + (cb ^ ((row & 7) << 4)));
      }
#pragma unroll
      for (int nf = 0; nf < 4; nf++) {
        int row = nf * 16 + (lane & 15);
        bf[nf] = *(const f16x8*)((const char*)Blds + row * 128 + (cb ^ ((row & 7) << 4)));
      }
#pragma unroll
      for (int mf = 0; mf < 2; mf++)
#pragma unroll
        for (int nf = 0; nf < 4; nf++) acc[mf][nf] = MFMA16(af[mf], bf[nf], acc[mf][nf]);
    }
  }
#pragma unroll
  for (int mf = 0; mf < 2; mf++)
#pragma unroll
    for (int nf = 0; nf < 4; nf++)
#pragma unroll
      for (int r = 0; r < 4; r++) {
        int n = nt * 128 + wave * 32 + mf * 16 + (lane >> 4) * 4 + r;
        int ch = nf * 16 + (lane & 15);
        Q[(((size_t)b * 4096 + n) << 6) + ch] = (f16)acc[mf][nf][r];
      }
}

// -------------------------------------------------------------------------
// phi+g proj (full res): F[b][jj][n] = sum_k Wproj[64+jj][k] * xT[b][n][k],
// jj in [0,320). Tile: 64ch x 128n, 4 waves as 2x2 each [32ch x 64n].
__global__ void k_gemm_proj(const f16* __restrict__ xT, const f16* __restrict__ Wproj,
                            f16* __restrict__ F) {
  __shared__ f16 Alds[64 * 64];
  __shared__ f16 Blds[128 * 64];
  int b = blockIdx.z, mt = blockIdx.y, nt = blockIdx.x;
  int lane = threadIdx.x & 63, wave = threadIdx.x >> 6;
  int wm = wave >> 1, wn = wave & 1;
  f32x4 acc[2][4];
#pragma unroll
  for (int mf = 0; mf < 2; mf++)
#pragma unroll
    for (int nf = 0; nf < 4; nf++) acc[mf][nf] = (f32x4){0, 0, 0, 0};
  const f16* Abase = Wproj + ((64 + mt * 64) << 8);
  const f16* Bbase = xT + (((size_t)b * 4096 + nt * 128) << 8);
  for (int k0 = 0; k0 < 256; k0 += 64) {
    __syncthreads();
#pragma unroll
    for (int i = 0; i < 2; i++) {
      int chunk = i * 256 + threadIdx.x;
      int row = chunk >> 3, cc = chunk & 7, scc = cc ^ (row & 7);
      gload16(Abase + (row << 8) + k0 + scc * 8, (char*)Alds + (i * 256 + wave * 64) * 16);
    }
#pragma unroll
    for (int i = 0; i < 4; i++) {
      int chunk = i * 256 + threadIdx.x;
      int row = chunk >> 3, cc = chunk & 7, scc = cc ^ (row & 7);
      gload16(Bbase + (row << 8) + k0 + scc * 8, (char*)Blds + (i * 256 + wave * 64) * 16);
    }
    __syncthreads();
#pragma unroll
    for (int ks = 0; ks < 2; ks++) {
      int cb = ((lane >> 4) * 8 + ks * 32) * 2;
      f16x8 af[2], bf[4];
#pragma unroll
      for (int mf = 0; mf < 2; mf++) {
        int row = wm * 32 + mf * 16 + (lane & 15);
        af[mf] = *(const f16x8*)((const char*)Alds + row * 128 + (cb ^ ((row & 7) << 4)));
      }
#pragma unroll
      for (int nf = 0; nf < 4; nf++) {
        int row = wn * 64 + nf * 16 + (lane & 15);
        bf[nf] = *(const f16x8*)((const char*)Blds + row * 128 + (cb ^ ((row & 7) << 4)));
      }
#pragma unroll
      for (int mf = 0; mf < 2; mf++)
#pragma unroll
        for (int nf = 0; nf < 4; nf++) acc[mf][nf] = MFMA16(af[mf], bf[nf], acc[mf][nf]);
    }
  }
#pragma unroll
  for (int mf = 0; mf < 2; mf++)
#pragma unroll
    for (int nf = 0; nf < 4; nf++)
#pragma unroll
      for (int r = 0; r < 4; r++) {
        int jj = mt * 64 + wm * 32 + mf * 16 + (lane >> 4) * 4 + r;
        int n = nt * 128 + wn * 64 + nf * 16 + (lane & 15);
        F[(((size_t)b * 320 + jj) << 12) + n] = (f16)acc[mf][nf][r];
      }
}

// -------------------------------------------------------------------------
// 2x2 maxpool: F[b][jj][4096] -> jj<64: Kp[b][m][jj] (phi), jj>=64: V[b][jj-64][m] (g).
// One task = (b, jj, ph): pools two spatial rows (128 f16) into 32 outputs.
__global__ void k_pool(const f16* __restrict__ F, f16* __restrict__ Kp,
                       f16* __restrict__ V) {
  int id = blockIdx.x * 256 + threadIdx.x;  // < 8*320*32 = 81920
  int ph = id & 31;
  int rest = id >> 5;
  int jj = rest % 320;
  int b = rest / 320;
  const f16x8* r0 = (const f16x8*)(F + (((size_t)b * 320 + jj) << 12) + ph * 128);
  const f16x8* r1 = r0 + 8;  // next spatial row (+64 f16)
  f16 outv[32];
#pragma unroll
  for (int ch = 0; ch < 8; ch++) {
    f16x8 u = r0[ch], v = r1[ch];
#pragma unroll
    for (int p = 0; p < 4; p++) {
      float m1 = fmaxf(fmaxf((float)u[2 * p], (float)u[2 * p + 1]),
                       fmaxf((float)v[2 * p], (float)v[2 * p + 1]));
      outv[ch * 4 + p] = (f16)m1;
    }
  }
  int m0 = ph * 32;
  if (jj < 64) {
#pragma unroll
    for (int p = 0; p < 32; p++)
      Kp[((size_t)b * 1024 + m0 + p) * 64 + jj] = outv[p];
  } else {
    f16* dst = V + (((size_t)b * 256 + (jj - 64)) << 10) + m0;
#pragma unroll
    for (int c8 = 0; c8 < 4; c8++) {
      f16x8 w;
#pragma unroll
      for (int i = 0; i < 8; i++) w[i] = outv[c8 * 8 + i];
      *(f16x8*)(dst + c8 * 8) = w;
    }
  }
}

// -------------------------------------------------------------------------
// Flash attention per batch: Q [4096][64], K [1024][64], V [256][1024] ->
// att [b][n][c] fp16. Block = 64 Q-rows (4 waves x 16 rows), KV tile = 64 keys.
__global__ void k_flash(const f16* __restrict__ Q, const f16* __restrict__ Kp,
                        const f16* __restrict__ V, f16* __restrict__ att) {
  __shared__ f16 Klds[64 * 64];    // [m][c], swizzled
  __shared__ f16 Vlds[256 * 64];   // [c][m], swizzled
  __shared__ f16 Plds[4][16 * 72]; // per-wave P [n][m], padded
  int b = blockIdx.y, qt = blockIdx.x;
  int lane = threadIdx.x & 63, wave = threadIdx.x >> 6;
  const f16* Qrow = Q + (((size_t)b * 4096 + qt * 64 + wave * 16 + (lane & 15)) << 6);
  f16x8 qf[2];
  qf[0] = *(const f16x8*)(Qrow + (lane >> 4) * 8);
  qf[1] = *(const f16x8*)(Qrow + 32 + (lane >> 4) * 8);
  const f16* Kb = Kp + ((size_t)b << 16);
  const f16* Vb = V + ((size_t)b << 18);
  f32x4 o[16];
#pragma unroll
  for (int i = 0; i < 16; i++) o[i] = (f32x4){0, 0, 0, 0};
  float mrow[4] = {-1e30f, -1e30f, -1e30f, -1e30f};
  float lrow[4] = {0.f, 0.f, 0.f, 0.f};
  for (int kt = 0; kt < 16; ++kt) {
    __syncthreads();
#pragma unroll
    for (int i = 0; i < 2; i++) {
      int chunk = i * 256 + threadIdx.x;
      int row = chunk >> 3, cc = chunk & 7, scc = cc ^ (row & 7);
      gload16(Kb + ((kt * 64 + row) << 6) + scc * 8, (char*)Klds + (i * 256 + wave * 64) * 16);
    }
#pragma unroll
    for (int i = 0; i < 8; i++) {
      int chunk = i * 256 + threadIdx.x;
      int row = chunk >> 3, cc = chunk & 7, scc = cc ^ (row & 7);
      gload16(Vb + ((size_t)row << 10) + kt * 64 + scc * 8,
              (char*)Vlds + (i * 256 + wave * 64) * 16);
    }
    __syncthreads();
    // S = Q K^T  (S[mf] col=m=lane&15, row n=(lane>>4)*4+r)
    f32x4 s[4];
#pragma unroll
    for (int mf = 0; mf < 4; mf++) s[mf] = (f32x4){0, 0, 0, 0};
#pragma unroll
    for (int ks = 0; ks < 2; ks++) {
      int cb = ((lane >> 4) * 8 + ks * 32) * 2;
#pragma unroll
      for (int mf = 0; mf < 4; mf++) {
        int row = mf * 16 + (lane & 15);
        f16x8 bf = *(const f16x8*)((const char*)Klds + row * 128 + (cb ^ ((row & 7) << 4)));
        s[mf] = MFMA16(qf[ks], bf, s[mf]);
      }
    }
    // online softmax over this key tile (row reduce = over lanes 0..15 of group)
    float e[4][4];
#pragma unroll
    for (int r = 0; r < 4; r++) {
      float v = fmaxf(fmaxf(s[0][r], s[1][r]), fmaxf(s[2][r], s[3][r]));
      v = fmaxf(v, __shfl_xor(v, 1));
      v = fmaxf(v, __shfl_xor(v, 2));
      v = fmaxf(v, __shfl_xor(v, 4));
      v = fmaxf(v, __shfl_xor(v, 8));
      float mnew = fmaxf(mrow[r], v);
      float corr = exp2f((mrow[r] - mnew) * 1.44269504f);
      float sum = 0.f;
#pragma unroll
      for (int mf = 0; mf < 4; mf++) {
        float ev = exp2f((s[mf][r] - mnew) * 1.44269504f);
        e[mf][r] = ev;
        sum += ev;
      }
      sum += __shfl_xor(sum, 1);
      sum += __shfl_xor(sum, 2);
      sum += __shfl_xor(sum, 4);
      sum += __shfl_xor(sum, 8);
      lrow[r] = lrow[r] * corr + sum;
      mrow[r] = mnew;
#pragma unroll
      for (int cf = 0; cf < 16; cf++) o[cf][r] *= corr;
    }
    // P -> per-wave LDS [n][m] (fp16), then PV
    f16* P = &Plds[wave][0];
    int prow = (lane >> 4) * 4;
#pragma unroll
    for (int mf = 0; mf < 4; mf++)
#pragma unroll
      for (int r = 0; r < 4; r++)
        P[(prow + r) * 72 + mf * 16 + (lane & 15)] = (f16)e[mf][r];
#pragma unroll
    for (int ks = 0; ks < 2; ks++) {
      f16x8 af = *(const f16x8*)(P + (lane & 15) * 72 + (lane >> 4) * 8 + ks * 32);
      int cb = ((lane >> 4) * 8 + ks * 32) * 2;
#pragma unroll
      for (int cf = 0; cf < 16; cf++) {
        int row = cf * 16 + (lane & 15);
        f16x8 bf = *(const f16x8*)((const char*)Vlds + row * 128 + (cb ^ ((row & 7) << 4)));
        o[cf] = MFMA16(af, bf, o[cf]);
      }
    }
  }
  int nbase = qt * 64 + wave * 16 + (lane >> 4) * 4;
#pragma unroll
  for (int r = 0; r < 4; r++) {
    float inv = 1.f / lrow[r];
#pragma unroll
    for (int cf = 0; cf < 16; cf++) {
      int n = nbase + r;
      int c = cf * 16 + (lane & 15);
      att[(((size_t)b * 4096 + n) << 8) + c] = (f16)(o[cf][r] * inv);
    }
  }
}

// -------------------------------------------------------------------------
// Output GEMM: out[b][o][n] = sum_{k<512} Wcat[o][k] * Bcat[n][k],
// Bcat = [att | xT]. Tile 128o x 128n, BK=64, 4 waves as 2x2 each [64 x 64].
__global__ void k_gemm_out(const f16* __restrict__ Wcat, const f16* __restrict__ att,
                           const f16* __restrict__ xT, float* __restrict__ out) {
  __shared__ f16 Alds[128 * 64];
  __shared__ f16 Blds[128 * 64];
  int b = blockIdx.z, mt = blockIdx.y, nt = blockIdx.x;
  int lane = threadIdx.x & 63, wave = threadIdx.x >> 6;
  int wm = wave >> 1, wn = wave & 1;
  f32x4 acc[4][4];
#pragma unroll
  for (int mf = 0; mf < 4; mf++)
#pragma unroll
    for (int nf = 0; nf < 4; nf++) acc[mf][nf] = (f32x4){0, 0, 0, 0};
  const f16* Abase = Wcat + (size_t)(mt * 128) * 512;
  for (int k0 = 0; k0 < 512; k0 += 64) {
    __syncthreads();
#pragma unroll
    for (int i = 0; i < 4; i++) {
      int chunk = i * 256 + threadIdx.x;
      int row = chunk >> 3, cc = chunk & 7, scc = cc ^ (row & 7);
      gload16(Abase + row * 512 + k0 + scc * 8, (char*)Alds + (i * 256 + wave * 64) * 16);
    }
    const f16* Bcol = (k0 < 256) ? (att + (((size_t)b * 4096 + nt * 128) << 8))
                                 : (xT + (((size_t)b * 4096 + nt * 128) << 8));
    int kk = (k0 < 256) ? k0 : (k0 - 256);
#pragma unroll
    for (int i = 0; i < 4; i++) {
      int chunk = i * 256 + threadIdx.x;
      int row = chunk >> 3, cc = chunk & 7, scc = cc ^ (row & 7);
      gload16(Bcol + (row << 8) + kk + scc * 8, (char*)Blds + (i * 256 + wave * 64) * 16);
    }
    __syncthreads();
#pragma unroll
    for (int ks = 0; ks < 2; ks++) {
      int cb = ((lane >> 4) * 8 + ks * 32) * 2;
      f16x8 af[4], bf[4];
#pragma unroll
      for (int mf = 0; mf < 4; mf++) {
        int row = wm * 64 + mf * 16 + (lane & 15);
        af[mf] = *(const f16x8*)((const char*)Alds + row * 128 + (cb ^ ((row & 7) << 4)));
      }
#pragma unroll
      for (int nf = 0; nf < 4; nf++) {
        int row = wn * 64 + nf * 16 + (lane & 15);
        bf[nf] = *(const f16x8*)((const char*)Blds + row * 128 + (cb ^ ((row & 7) << 4)));
      }
#pragma unroll
      for (int mf = 0; mf < 4; mf++)
#pragma unroll
        for (int nf = 0; nf < 4; nf++) acc[mf][nf] = MFMA16(af[mf], bf[nf], acc[mf][nf]);
    }
  }
#pragma unroll
  for (int mf = 0; mf < 4; mf++)
#pragma unroll
    for (int nf = 0; nf < 4; nf++)
#pragma unroll
      for (int r = 0; r < 4; r++) {
        int oo = mt * 128 + wm * 64 + mf * 16 + (lane >> 4) * 4 + r;
        int n = nt * 128 + wn * 64 + nf * 16 + (lane & 15);
        out[(((size_t)b * 512 + oo) << 12) + n] = acc[mf][nf][r];
      }
}

// -------------------------------------------------------------------------
extern "C" void kernel_launch(void* const* d_in, const int* in_sizes, int n_in,
                              void* d_out, int out_size, void* d_ws, size_t ws_size,
                              hipStream_t stream) {
  const float* x = (const float*)d_in[0];
  const float* wt = (const float*)d_in[1];
  const float* wp = (const float*)d_in[2];
  const float* wg = (const float*)d_in[3];
  const float* wo = (const float*)d_in[4];
  const float* wr = (const float*)d_in[5];
  const float* gm = (const float*)d_in[6];
  float* out = (float*)d_out;
  char* ws = (char*)d_ws;
  const size_t MB = 1024 * 1024;
  f16* xT = (f16*)(ws);
  f16* Qb = (f16*)(ws + 16 * MB);
  f16* Kp = (f16*)(ws + 20 * MB);
  f16* Vb = (f16*)(ws + 21 * MB);
  f16* Wproj = (f16*)(ws + 25 * MB);
  f16* Wcat = (f16*)(ws + 25 * MB + 512 * 1024);
  f16* F = (f16*)(ws + 26 * MB);
  f16* att = F;  // alias: F fully consumed by k_pool before k_flash writes att

  hipLaunchKernelGGL(k_prep_w, dim3(1408), dim3(256), 0, stream, wt, wp, wg, wo, wr, gm,
                     Wproj, Wcat);
  hipLaunchKernelGGL(k_transpose, dim3(4, 64, 8), dim3(256), 0, stream, x, xT);
  hipLaunchKernelGGL(k_gemm_q, dim3(32, 8), dim3(256), 0, stream, xT, Wproj, Qb);
  hipLaunchKernelGGL(k_gemm_proj, dim3(32, 5, 8), dim3(256), 0, stream, xT, Wproj, F);
  hipLaunchKernelGGL(k_pool, dim3(320), dim3(256), 0, stream, F, Kp, Vb);
  hipLaunchKernelGGL(k_flash, dim3(64, 8), dim3(256), 0, stream, Qb, Kp, Vb, att);
  hipLaunchKernelGGL(k_gemm_out, dim3(32, 4, 8), dim3(256), 0, stream, Wcat, att, xT, out);
}

// Round 2
// 140.221 us; speedup vs baseline: 1.3611x; 1.3611x over previous
//
#include <hip/hip_runtime.h>

// NonLocalBlock (SAGAN non-local) fused pipeline for MI355X / gfx950.
// B=8, Cin=256, H=W=64 (HW=4096), Cout=512. All GEMMs via fp16 MFMA
// (16x16x32, fp32 accum). Workspace layout (needs ~46 MB of d_ws):
//   [0,16MB)   xT   fp16 [8][4096][256]   (x transposed, n-major)
//   [16,20MB)  Q    fp16 [8][4096][64]
//   [20,21MB)  Kp   fp16 [8][1024][64]
//   [21,25MB)  V    fp16 [8][256][1024]
//   [25MB+0)   Wproj fp16 [384][256]  (theta|phi|g, pre-scaled)
//   [25MB+512K) Wcat fp16 [512][512]  (gamma*s/sqrt2*w_o | s/sqrt2*w_res)
//   [26,46MB)  F    fp16 [8][320][4096] full-res phi|g proj; att aliases here
//
// R1->R2: added __launch_bounds__ to every kernel. Without it the compiler
// capped k_flash (and the GEMMs) at 64 VGPRs and spilled the 64-reg f32x4
// accumulator to scratch (rocprof: VGPR_Count=64, WRITE_SIZE 84MB vs 17MB
// expected). (256,2) -> 256-VGPR cap, fits the ~150-reg working set.

typedef _Float16 f16;
typedef f16 f16x8 __attribute__((ext_vector_type(8)));
typedef float f32x4 __attribute__((ext_vector_type(4)));

#define MFMA16(a, b, c) __builtin_amdgcn_mfma_f32_16x16x32_f16((a), (b), (c), 0, 0, 0)

__device__ __forceinline__ void gload16(const void* src, void* dst_lds) {
  __builtin_amdgcn_global_load_lds(
      (const __attribute__((address_space(1))) void*)src,
      (__attribute__((address_space(3))) void*)dst_lds, 16, 0, 0);
}

// -------------------------------------------------------------------------
__global__ __launch_bounds__(256, 4)
void k_prep_w(const float* __restrict__ wt, const float* __restrict__ wp,
              const float* __restrict__ wg, const float* __restrict__ wo,
              const float* __restrict__ wr, const float* __restrict__ gamma,
              f16* __restrict__ Wproj, f16* __restrict__ Wcat) {
  int i = blockIdx.x * 256 + threadIdx.x;
  const float s = 0.08838834764831845f;    // sqrt(2/256)
  const float is2 = 0.7071067811865476f;   // 1/sqrt(2)
  if (i < 384 * 256) {
    float v = (i < 64 * 256) ? wt[i]
              : (i < 128 * 256 ? wp[i - 64 * 256] : wg[i - 128 * 256]);
    Wproj[i] = (f16)(v * s);
  } else {
    int j = i - 384 * 256;
    if (j < 512 * 512) {
      int r = j >> 9, c = j & 511;
      float v = (c < 256) ? wo[r * 256 + c] * (gamma[0] * s * is2)
                          : wr[r * 256 + (c - 256)] * (s * is2);
      Wcat[j] = (f16)v;
    }
  }
}

// -------------------------------------------------------------------------
// Transpose x [b][256][4096] fp32 -> xT [b][4096][256] fp16 via 64x64 LDS tiles.
__global__ __launch_bounds__(256, 4)
void k_transpose(const float* __restrict__ x, f16* __restrict__ xT) {
  __shared__ f16 tile[64 * 72];
  int b = blockIdx.z, nt = blockIdx.y, ct = blockIdx.x;
  int t = threadIdx.x;
  {
    int c = t >> 2, nch = (t & 3) * 16;
    const float* src = x + (((size_t)b * 256 + ct * 64 + c) << 12) + nt * 64 + nch;
    float4 v0 = *(const float4*)(src);
    float4 v1 = *(const float4*)(src + 4);
    float4 v2 = *(const float4*)(src + 8);
    float4 v3 = *(const float4*)(src + 12);
    f16x8 a = {(f16)v0.x, (f16)v0.y, (f16)v0.z, (f16)v0.w,
               (f16)v1.x, (f16)v1.y, (f16)v1.z, (f16)v1.w};
    f16x8 bb = {(f16)v2.x, (f16)v2.y, (f16)v2.z, (f16)v2.w,
                (f16)v3.x, (f16)v3.y, (f16)v3.z, (f16)v3.w};
    *(f16x8*)&tile[c * 72 + nch] = a;
    *(f16x8*)&tile[c * 72 + nch + 8] = bb;
  }
  __syncthreads();
  {
    int n = t >> 2, cch = (t & 3) * 16;
    f16 tmp[16];
#pragma unroll
    for (int i = 0; i < 16; i++) tmp[i] = tile[(cch + i) * 72 + n];
    f16x8 a, bb;
#pragma unroll
    for (int i = 0; i < 8; i++) { a[i] = tmp[i]; bb[i] = tmp[8 + i]; }
    f16* dst = xT + (((size_t)b * 4096 + nt * 64 + n) << 8) + ct * 64 + cch;
    *(f16x8*)dst = a;
    *(f16x8*)(dst + 8) = bb;
  }
}

// -------------------------------------------------------------------------
// Q GEMM: Q[b][n][ch] = sum_k xT[b][n][k] * Wproj[ch][k], ch in [0,64).
__global__ __launch_bounds__(256, 2)
void k_gemm_q(const f16* __restrict__ xT, const f16* __restrict__ Wproj,
              f16* __restrict__ Q) {
  __shared__ f16 Alds[128 * 64];
  __shared__ f16 Blds[64 * 64];
  int b = blockIdx.y, nt = blockIdx.x;
  int lane = threadIdx.x & 63, wave = threadIdx.x >> 6;
  f32x4 acc[2][4];
#pragma unroll
  for (int mf = 0; mf < 2; mf++)
#pragma unroll
    for (int nf = 0; nf < 4; nf++) acc[mf][nf] = (f32x4){0, 0, 0, 0};
  const f16* Abase = xT + (((size_t)b * 4096 + nt * 128) << 8);
  for (int k0 = 0; k0 < 256; k0 += 64) {
    __syncthreads();
#pragma unroll
    for (int i = 0; i < 4; i++) {
      int chunk = i * 256 + threadIdx.x;
      int row = chunk >> 3, cc = chunk & 7, scc = cc ^ (row & 7);
      gload16(Abase + (row << 8) + k0 + scc * 8, (char*)Alds + (i * 256 + wave * 64) * 16);
    }
#pragma unroll
    for (int i = 0; i < 2; i++) {
      int chunk = i * 256 + threadIdx.x;
      int row = chunk >> 3, cc = chunk & 7, scc = cc ^ (row & 7);
      gload16(Wproj + (row << 8) + k0 + scc * 8, (char*)Blds + (i * 256 + wave * 64) * 16);
    }
    __syncthreads();
#pragma unroll
    for (int ks = 0; ks < 2; ks++) {
      int cb = ((lane >> 4) * 8 + ks * 32) * 2;
      f16x8 af[2], bf[4];
#pragma unroll
      for (int mf = 0; mf < 2; mf++) {
        int row = wave * 32 + mf * 16 + (lane & 15);
        af[mf] = *(const f16x8*)((const char*)Alds + row * 128 + (cb ^ ((row & 7) << 4)));
      }
#pragma unroll
      for (int nf = 0; nf < 4; nf++) {
        int row = nf * 16 + (lane & 15);
        bf[nf] = *(const f16x8*)((const char*)Blds + row * 128 + (cb ^ ((row & 7) << 4)));
      }
#pragma unroll
      for (int mf = 0; mf < 2; mf++)
#pragma unroll
        for (int nf = 0; nf < 4; nf++) acc[mf][nf] = MFMA16(af[mf], bf[nf], acc[mf][nf]);
    }
  }
#pragma unroll
  for (int mf = 0; mf < 2; mf++)
#pragma unroll
    for (int nf = 0; nf < 4; nf++)
#pragma unroll
      for (int r = 0; r < 4; r++) {
        int n = nt * 128 + wave * 32 + mf * 16 + (lane >> 4) * 4 + r;
        int ch = nf * 16 + (lane & 15);
        Q[(((size_t)b * 4096 + n) << 6) + ch] = (f16)acc[mf][nf][r];
      }
}

// -------------------------------------------------------------------------
// phi+g proj (full res): F[b][jj][n] = sum_k Wproj[64+jj][k] * xT[b][n][k].
__global__ __launch_bounds__(256, 2)
void k_gemm_proj(const f16* __restrict__ xT, const f16* __restrict__ Wproj,
                 f16* __restrict__ F) {
  __shared__ f16 Alds[64 * 64];
  __shared__ f16 Blds[128 * 64];
  int b = blockIdx.z, mt = blockIdx.y, nt = blockIdx.x;
  int lane = threadIdx.x & 63, wave = threadIdx.x >> 6;
  int wm = wave >> 1, wn = wave & 1;
  f32x4 acc[2][4];
#pragma unroll
  for (int mf = 0; mf < 2; mf++)
#pragma unroll
    for (int nf = 0; nf < 4; nf++) acc[mf][nf] = (f32x4){0, 0, 0, 0};
  const f16* Abase = Wproj + ((64 + mt * 64) << 8);
  const f16* Bbase = xT + (((size_t)b * 4096 + nt * 128) << 8);
  for (int k0 = 0; k0 < 256; k0 += 64) {
    __syncthreads();
#pragma unroll
    for (int i = 0; i < 2; i++) {
      int chunk = i * 256 + threadIdx.x;
      int row = chunk >> 3, cc = chunk & 7, scc = cc ^ (row & 7);
      gload16(Abase + (row << 8) + k0 + scc * 8, (char*)Alds + (i * 256 + wave * 64) * 16);
    }
#pragma unroll
    for (int i = 0; i < 4; i++) {
      int chunk = i * 256 + threadIdx.x;
      int row = chunk >> 3, cc = chunk & 7, scc = cc ^ (row & 7);
      gload16(Bbase + (row << 8) + k0 + scc * 8, (char*)Blds + (i * 256 + wave * 64) * 16);
    }
    __syncthreads();
#pragma unroll
    for (int ks = 0; ks < 2; ks++) {
      int cb = ((lane >> 4) * 8 + ks * 32) * 2;
      f16x8 af[2], bf[4];
#pragma unroll
      for (int mf = 0; mf < 2; mf++) {
        int row = wm * 32 + mf * 16 + (lane & 15);
        af[mf] = *(const f16x8*)((const char*)Alds + row * 128 + (cb ^ ((row & 7) << 4)));
      }
#pragma unroll
      for (int nf = 0; nf < 4; nf++) {
        int row = wn * 64 + nf * 16 + (lane & 15);
        bf[nf] = *(const f16x8*)((const char*)Blds + row * 128 + (cb ^ ((row & 7) << 4)));
      }
#pragma unroll
      for (int mf = 0; mf < 2; mf++)
#pragma unroll
        for (int nf = 0; nf < 4; nf++) acc[mf][nf] = MFMA16(af[mf], bf[nf], acc[mf][nf]);
    }
  }
#pragma unroll
  for (int mf = 0; mf < 2; mf++)
#pragma unroll
    for (int nf = 0; nf < 4; nf++)
#pragma unroll
      for (int r = 0; r < 4; r++) {
        int jj = mt * 64 + wm * 32 + mf * 16 + (lane >> 4) * 4 + r;
        int n = nt * 128 + wn * 64 + nf * 16 + (lane & 15);
        F[(((size_t)b * 320 + jj) << 12) + n] = (f16)acc[mf][nf][r];
      }
}

// -------------------------------------------------------------------------
// 2x2 maxpool: F[b][jj][4096] -> jj<64: Kp[b][m][jj] (phi), jj>=64: V[b][jj-64][m].
__global__ __launch_bounds__(256, 4)
void k_pool(const f16* __restrict__ F, f16* __restrict__ Kp, f16* __restrict__ V) {
  int id = blockIdx.x * 256 + threadIdx.x;  // < 8*320*32 = 81920
  int ph = id & 31;
  int rest = id >> 5;
  int jj = rest % 320;
  int b = rest / 320;
  const f16x8* r0 = (const f16x8*)(F + (((size_t)b * 320 + jj) << 12) + ph * 128);
  const f16x8* r1 = r0 + 8;
  f16 outv[32];
#pragma unroll
  for (int ch = 0; ch < 8; ch++) {
    f16x8 u = r0[ch], v = r1[ch];
#pragma unroll
    for (int p = 0; p < 4; p++) {
      float m1 = fmaxf(fmaxf((float)u[2 * p], (float)u[2 * p + 1]),
                       fmaxf((float)v[2 * p], (float)v[2 * p + 1]));
      outv[ch * 4 + p] = (f16)m1;
    }
  }
  int m0 = ph * 32;
  if (jj < 64) {
#pragma unroll
    for (int p = 0; p < 32; p++)
      Kp[((size_t)b * 1024 + m0 + p) * 64 + jj] = outv[p];
  } else {
    f16* dst = V + (((size_t)b * 256 + (jj - 64)) << 10) + m0;
#pragma unroll
    for (int c8 = 0; c8 < 4; c8++) {
      f16x8 w;
#pragma unroll
      for (int i = 0; i < 8; i++) w[i] = outv[c8 * 8 + i];
      *(f16x8*)(dst + c8 * 8) = w;
    }
  }
}

// -------------------------------------------------------------------------
// Flash attention per batch: Q [4096][64], K [1024][64], V [256][1024] ->
// att [b][n][c] fp16. Block = 64 Q-rows (4 waves x 16 rows), KV tile = 64 keys.
__global__ __launch_bounds__(256, 2)
void k_flash(const f16* __restrict__ Q, const f16* __restrict__ Kp,
             const f16* __restrict__ V, f16* __restrict__ att) {
  __shared__ f16 Klds[64 * 64];    // [m][c], swizzled
  __shared__ f16 Vlds[256 * 64];   // [c][m], swizzled
  __shared__ f16 Plds[4][16 * 72]; // per-wave P [n][m], padded
  int b = blockIdx.y, qt = blockIdx.x;
  int lane = threadIdx.x & 63, wave = threadIdx.x >> 6;
  const f16* Qrow = Q + (((size_t)b * 4096 + qt * 64 + wave * 16 + (lane & 15)) << 6);
  f16x8 qf[2];
  qf[0] = *(const f16x8*)(Qrow + (lane >> 4) * 8);
  qf[1] = *(const f16x8*)(Qrow + 32 + (lane >> 4) * 8);
  const f16* Kb = Kp + ((size_t)b << 16);
  const f16* Vb = V + ((size_t)b << 18);
  f32x4 o[16];
#pragma unroll
  for (int i = 0; i < 16; i++) o[i] = (f32x4){0, 0, 0, 0};
  float mrow[4] = {-1e30f, -1e30f, -1e30f, -1e30f};
  float lrow[4] = {0.f, 0.f, 0.f, 0.f};
  for (int kt = 0; kt < 16; ++kt) {
    __syncthreads();
#pragma unroll
    for (int i = 0; i < 2; i++) {
      int chunk = i * 256 + threadIdx.x;
      int row = chunk >> 3, cc = chunk & 7, scc = cc ^ (row & 7);
      gload16(Kb + ((kt * 64 + row) << 6) + scc * 8, (char*)Klds + (i * 256 + wave * 64) * 16);
    }
#pragma unroll
    for (int i = 0; i < 8; i++) {
      int chunk = i * 256 + threadIdx.x;
      int row = chunk >> 3, cc = chunk & 7, scc = cc ^ (row & 7);
      gload16(Vb + ((size_t)row << 10) + kt * 64 + scc * 8,
              (char*)Vlds + (i * 256 + wave * 64) * 16);
    }
    __syncthreads();
    // S = Q K^T
    f32x4 s[4];
#pragma unroll
    for (int mf = 0; mf < 4; mf++) s[mf] = (f32x4){0, 0, 0, 0};
#pragma unroll
    for (int ks = 0; ks < 2; ks++) {
      int cb = ((lane >> 4) * 8 + ks * 32) * 2;
#pragma unroll
      for (int mf = 0; mf < 4; mf++) {
        int row = mf * 16 + (lane & 15);
        f16x8 bf = *(const f16x8*)((const char*)Klds + row * 128 + (cb ^ ((row & 7) << 4)));
        s[mf] = MFMA16(qf[ks], bf, s[mf]);
      }
    }
    // online softmax over this key tile
    float e[4][4];
#pragma unroll
    for (int r = 0; r < 4; r++) {
      float v = fmaxf(fmaxf(s[0][r], s[1][r]), fmaxf(s[2][r], s[3][r]));
      v = fmaxf(v, __shfl_xor(v, 1));
      v = fmaxf(v, __shfl_xor(v, 2));
      v = fmaxf(v, __shfl_xor(v, 4));
      v = fmaxf(v, __shfl_xor(v, 8));
      float mnew = fmaxf(mrow[r], v);
      float corr = exp2f((mrow[r] - mnew) * 1.44269504f);
      float sum = 0.f;
#pragma unroll
      for (int mf = 0; mf < 4; mf++) {
        float ev = exp2f((s[mf][r] - mnew) * 1.44269504f);
        e[mf][r] = ev;
        sum += ev;
      }
      sum += __shfl_xor(sum, 1);
      sum += __shfl_xor(sum, 2);
      sum += __shfl_xor(sum, 4);
      sum += __shfl_xor(sum, 8);
      lrow[r] = lrow[r] * corr + sum;
      mrow[r] = mnew;
#pragma unroll
      for (int cf = 0; cf < 16; cf++) o[cf][r] *= corr;
    }
    // P -> per-wave LDS [n][m] (fp16), then PV
    f16* P = &Plds[wave][0];
    int prow = (lane >> 4) * 4;
#pragma unroll
    for (int mf = 0; mf < 4; mf++)
#pragma unroll
      for (int r = 0; r < 4; r++)
        P[(prow + r) * 72 + mf * 16 + (lane & 15)] = (f16)e[mf][r];
#pragma unroll
    for (int ks = 0; ks < 2; ks++) {
      f16x8 af = *(const f16x8*)(P + (lane & 15) * 72 + (lane >> 4) * 8 + ks * 32);
      int cb = ((lane >> 4) * 8 + ks * 32) * 2;
#pragma unroll
      for (int cf = 0; cf < 16; cf++) {
        int row = cf * 16 + (lane & 15);
        f16x8 bf = *(const f16x8*)((const char*)Vlds + row * 128 + (cb ^ ((row & 7) << 4)));
        o[cf] = MFMA16(af, bf, o[cf]);
      }
    }
  }
  int nbase = qt * 64 + wave * 16 + (lane >> 4) * 4;
#pragma unroll
  for (int r = 0; r < 4; r++) {
    float inv = 1.f / lrow[r];
#pragma unroll
    for (int cf = 0; cf < 16; cf++) {
      int n = nbase + r;
      int c = cf * 16 + (lane & 15);
      att[(((size_t)b * 4096 + n) << 8) + c] = (f16)(o[cf][r] * inv);
    }
  }
}

// -------------------------------------------------------------------------
// Output GEMM: out[b][o][n] = sum_{k<512} Wcat[o][k] * Bcat[n][k], Bcat=[att|xT].
__global__ __launch_bounds__(256, 2)
void k_gemm_out(const f16* __restrict__ Wcat, const f16* __restrict__ att,
                const f16* __restrict__ xT, float* __restrict__ out) {
  __shared__ f16 Alds[128 * 64];
  __shared__ f16 Blds[128 * 64];
  int b = blockIdx.z, mt = blockIdx.y, nt = blockIdx.x;
  int lane = threadIdx.x & 63, wave = threadIdx.x >> 6;
  int wm = wave >> 1, wn = wave & 1;
  f32x4 acc[4][4];
#pragma unroll
  for (int mf = 0; mf < 4; mf++)
#pragma unroll
    for (int nf = 0; nf < 4; nf++) acc[mf][nf] = (f32x4){0, 0, 0, 0};
  const f16* Abase = Wcat + (size_t)(mt * 128) * 512;
  for (int k0 = 0; k0 < 512; k0 += 64) {
    __syncthreads();
#pragma unroll
    for (int i = 0; i < 4; i++) {
      int chunk = i * 256 + threadIdx.x;
      int row = chunk >> 3, cc = chunk & 7, scc = cc ^ (row & 7);
      gload16(Abase + row * 512 + k0 + scc * 8, (char*)Alds + (i * 256 + wave * 64) * 16);
    }
    const f16* Bcol = (k0 < 256) ? (att + (((size_t)b * 4096 + nt * 128) << 8))
                                 : (xT + (((size_t)b * 4096 + nt * 128) << 8));
    int kk = (k0 < 256) ? k0 : (k0 - 256);
#pragma unroll
    for (int i = 0; i < 4; i++) {
      int chunk = i * 256 + threadIdx.x;
      int row = chunk >> 3, cc = chunk & 7, scc = cc ^ (row & 7);
      gload16(Bcol + (row << 8) + kk + scc * 8, (char*)Blds + (i * 256 + wave * 64) * 16);
    }
    __syncthreads();
#pragma unroll
    for (int ks = 0; ks < 2; ks++) {
      int cb = ((lane >> 4) * 8 + ks * 32) * 2;
      f16x8 af[4], bf[4];
#pragma unroll
      for (int mf = 0; mf < 4; mf++) {
        int row = wm * 64 + mf * 16 + (lane & 15);
        af[mf] = *(const f16x8*)((const char*)Alds + row * 128 + (cb ^ ((row & 7) << 4)));
      }
#pragma unroll
      for (int nf = 0; nf < 4; nf++) {
        int row = wn * 64 + nf * 16 + (lane & 15);
        bf[nf] = *(const f16x8*)((const char*)Blds + row * 128 + (cb ^ ((row & 7) << 4)));
      }
#pragma unroll
      for (int mf = 0; mf < 4; mf++)
#pragma unroll
        for (int nf = 0; nf < 4; nf++) acc[mf][nf] = MFMA16(af[mf], bf[nf], acc[mf][nf]);
    }
  }
#pragma unroll
  for (int mf = 0; mf < 4; mf++)
#pragma unroll
    for (int nf = 0; nf < 4; nf++)
#pragma unroll
      for (int r = 0; r < 4; r++) {
        int oo = mt * 128 + wm * 64 + mf * 16 + (lane >> 4) * 4 + r;
        int n = nt * 128 + wn * 64 + nf * 16 + (lane & 15);
        out[(((size_t)b * 512 + oo) << 12) + n] = acc[mf][nf][r];
      }
}

// -------------------------------------------------------------------------
extern "C" void kernel_launch(void* const* d_in, const int* in_sizes, int n_in,
                              void* d_out, int out_size, void* d_ws, size_t ws_size,
                              hipStream_t stream) {
  const float* x = (const float*)d_in[0];
  const float* wt = (const float*)d_in[1];
  const float* wp = (const float*)d_in[2];
  const float* wg = (const float*)d_in[3];
  const float* wo = (const float*)d_in[4];
  const float* wr = (const float*)d_in[5];
  const float* gm = (const float*)d_in[6];
  float* out = (float*)d_out;
  char* ws = (char*)d_ws;
  const size_t MB = 1024 * 1024;
  f16* xT = (f16*)(ws);
  f16* Qb = (f16*)(ws + 16 * MB);
  f16* Kp = (f16*)(ws + 20 * MB);
  f16* Vb = (f16*)(ws + 21 * MB);
  f16* Wproj = (f16*)(ws + 25 * MB);
  f16* Wcat = (f16*)(ws + 25 * MB + 512 * 1024);
  f16* F = (f16*)(ws + 26 * MB);
  f16* att = F;  // alias: F fully consumed by k_pool before k_flash writes att

  hipLaunchKernelGGL(k_prep_w, dim3(1408), dim3(256), 0, stream, wt, wp, wg, wo, wr, gm,
                     Wproj, Wcat);
  hipLaunchKernelGGL(k_transpose, dim3(4, 64, 8), dim3(256), 0, stream, x, xT);
  hipLaunchKernelGGL(k_gemm_q, dim3(32, 8), dim3(256), 0, stream, xT, Wproj, Qb);
  hipLaunchKernelGGL(k_gemm_proj, dim3(32, 5, 8), dim3(256), 0, stream, xT, Wproj, F);
  hipLaunchKernelGGL(k_pool, dim3(320), dim3(256), 0, stream, F, Kp, Vb);
  hipLaunchKernelGGL(k_flash, dim3(64, 8), dim3(256), 0, stream, Qb, Kp, Vb, att);
  hipLaunchKernelGGL(k_gemm_out, dim3(32, 4, 8), dim3(256), 0, stream, Wcat, att, xT, out);
}